// Round 8
// baseline (232.337 us; speedup 1.0000x reference)
//
#include <hip/hip_runtime.h>

#define N_NODES 100000
#define N_EDGES 1600000
#define BKT 128           // nodes per bucket == nodes per fused block
#define NBKT 782          // ceil(100000 / 128)
#define BKT_SHIFT 7
#define BKT_MASK 127
#define DL_SHIFT 17
#define SRC_MASK 0x1FFFF
#define CNT_BLOCKS 256    // edge chunks for count/scatter (6250 edges each)
#define CVT_BLOCKS 1563   // 1563*256*4 float4 >= 1.6M float4
#define ESRC_CAP 3072     // per-bucket edge capacity (mean 2048, +22 sigma)

typedef __attribute__((ext_vector_type(8))) short short8;
typedef __attribute__((ext_vector_type(4))) float float4v;

__device__ __forceinline__ unsigned short f2bf(float f) {  // RNE
  unsigned u = __float_as_uint(f);
  return (unsigned short)((u + 0x7fffu + ((u >> 16) & 1u)) >> 16);
}
__device__ __forceinline__ float bflo(unsigned d) { return __uint_as_float(d << 16); }
__device__ __forceinline__ float bfhi(unsigned d) { return __uint_as_float(d & 0xffff0000u); }

__device__ __forceinline__ void acc_add(float a[8], uint4 v) {
  a[0] += bflo(v.x); a[1] += bfhi(v.x);
  a[2] += bflo(v.y); a[3] += bfhi(v.y);
  a[4] += bflo(v.z); a[5] += bfhi(v.z);
  a[6] += bflo(v.w); a[7] += bfhi(v.w);
}
__device__ __forceinline__ void acc_fma(float a[8], uint4 v, float m) {
  a[0] = fmaf(m, bflo(v.x), a[0]); a[1] = fmaf(m, bfhi(v.x), a[1]);
  a[2] = fmaf(m, bflo(v.y), a[2]); a[3] = fmaf(m, bfhi(v.y), a[3]);
  a[4] = fmaf(m, bflo(v.z), a[4]); a[5] = fmaf(m, bfhi(v.z), a[5]);
  a[6] = fmaf(m, bflo(v.w), a[6]); a[7] = fmaf(m, bfhi(v.w), a[7]);
}

// ---- K1: bucket count (LDS hist, first) + weight pre-swizzle + cvt ---------

__global__ void k_prep_count(const float* __restrict__ in, unsigned short* __restrict__ outb,
                             const float* __restrict__ W0, const float* __restrict__ W1,
                             const float* __restrict__ W2, const float* __restrict__ W3,
                             unsigned short* __restrict__ F,
                             const int* __restrict__ dst, int* __restrict__ blkCnt) {
  __shared__ int hist[NBKT];
  const int bid = blockIdx.x;
  if (bid < CNT_BLOCKS) {
    for (int t = threadIdx.x; t < NBKT; t += 256) hist[t] = 0;
    __syncthreads();
    const int e0 = bid * (N_EDGES / CNT_BLOCKS);
    const int e1 = e0 + (N_EDGES / CNT_BLOCKS);
    for (int e = e0 + threadIdx.x; e < e1; e += 256)
      atomicAdd(&hist[dst[e] >> BKT_SHIFT], 1);
    __syncthreads();
    for (int t = threadIdx.x; t < NBKT; t += 256)
      blkCnt[t * CNT_BLOCKS + bid] = hist[t];
    return;
  }
  if (bid < CNT_BLOCKS + 4) {
    // weight pre-swizzle into MFMA B-fragment order
    if (threadIdx.x >= 64) return;
    const int wsel = bid - CNT_BLOCKS;
    const float* W = (wsel == 0) ? W0 : (wsel == 1) ? W1 : (wsel == 2) ? W2 : W3;
    unsigned short* out = F + wsel * 4096;
    int lane = threadIdx.x;
    int col = lane & 15, kr = lane >> 4;
    #pragma unroll
    for (int kc = 0; kc < 2; kc++)
      #pragma unroll
      for (int nt = 0; nt < 4; nt++) {
        unsigned d[4];
        #pragma unroll
        for (int jj = 0; jj < 4; jj++) {
          float w0 = W[(kc * 32 + kr * 8 + 2 * jj)     * 64 + nt * 16 + col];
          float w1 = W[(kc * 32 + kr * 8 + 2 * jj + 1) * 64 + nt * 16 + col];
          d[jj] = ((unsigned)f2bf(w1) << 16) | f2bf(w0);
        }
        uint4* p = (uint4*)(out + ((kc * 4 + nt) * 64 + lane) * 8);
        *p = make_uint4(d[0], d[1], d[2], d[3]);
      }
    return;
  }
  // cvt: 4 float4 per thread (coalesced per sub-iter)
  const int base = (bid - CNT_BLOCKS - 4) * 1024 + threadIdx.x;
  #pragma unroll
  for (int j = 0; j < 4; j++) {
    int i = base + j * 256;
    if (i < 1600000) {
      float4 v = ((const float4*)in)[i];
      unsigned d0 = ((unsigned)f2bf(v.y) << 16) | f2bf(v.x);
      unsigned d1 = ((unsigned)f2bf(v.w) << 16) | f2bf(v.z);
      ((uint2*)outb)[i] = make_uint2(d0, d1);
    }
  }
}

// ---- K2: per-bucket exclusive scan of per-block counts -> offsets + totals -

__global__ void kA_scan1(int* __restrict__ blkCnt, int* __restrict__ bktTot) {
  const int b = blockIdx.x;
  const int tid = threadIdx.x, lane = tid & 63, w = tid >> 6;
  __shared__ int wtot[4];
  int v = blkCnt[b * CNT_BLOCKS + tid];
  int inc = v;
  #pragma unroll
  for (int d = 1; d < 64; d <<= 1) { int y = __shfl_up(inc, d); if (lane >= d) inc += y; }
  if (lane == 63) wtot[w] = inc;
  __syncthreads();
  int base = 0;
  for (int j = 0; j < w; j++) base += wtot[j];
  blkCnt[b * CNT_BLOCKS + tid] = base + inc - v;
  if (tid == CNT_BLOCKS - 1) bktTot[b] = base + inc;
}

// ---- K3: scatter into bucket-grouped binned (LDS cursors, own offsets) -----

__global__ __launch_bounds__(512)
void k_scatter(const int* __restrict__ src, const int* __restrict__ dst,
               const int* __restrict__ blkCnt, const int* __restrict__ bktTot,
               int* __restrict__ bktStart, int* __restrict__ binned) {
  __shared__ int ps[NBKT];
  __shared__ int curb[NBKT];
  const int tid = threadIdx.x;
  const int bid = blockIdx.x;
  if (tid < 64) {
    int running = 0;
    for (int base = 0; base < NBKT; base += 64) {
      int i = base + tid;
      int v = (i < NBKT) ? bktTot[i] : 0;
      int inc = v;
      #pragma unroll
      for (int d = 1; d < 64; d <<= 1) { int y = __shfl_up(inc, d); if (tid >= d) inc += y; }
      if (i < NBKT) ps[i] = running + inc - v;
      running += __shfl(inc, 63);
    }
  }
  __syncthreads();
  for (int t = tid; t < NBKT; t += 512)
    curb[t] = ps[t] + blkCnt[t * CNT_BLOCKS + bid];
  if (bid == 0)
    for (int t = tid; t < NBKT; t += 512) bktStart[t] = ps[t];
  __syncthreads();
  const int e0 = bid * (N_EDGES / CNT_BLOCKS);
  const int e1 = e0 + (N_EDGES / CNT_BLOCKS);
  for (int e = e0 + tid; e < e1; e += 512) {
    int d = dst[e];
    int s = src[e];
    int p = atomicAdd(&curb[d >> BKT_SHIFT], 1);
    binned[p] = s | ((d & BKT_MASK) << DL_SHIFT);   // src:17 | dlocal:7
  }
}

// ---- fused per-layer, bucket-resident (both layers identical structure) ----
// block = 8 waves = one 128-node bucket: in-LDS counting sort of the bucket's
// edges -> esrc_l, aggregate from LDS indices, MFMA xform. No CSR in global.

template <bool RELU, bool OUT_BF>
__global__ __launch_bounds__(512)
void k_fusedB(const unsigned short* __restrict__ featb, const int* __restrict__ binned,
              const int* __restrict__ bktStart, const int* __restrict__ bktTot,
              const unsigned short* __restrict__ wfS, const unsigned short* __restrict__ wfN,
              const float* __restrict__ bias,
              float* __restrict__ outf, unsigned short* __restrict__ outb) {
  __shared__ int cnt[BKT];
  __shared__ int st[BKT];
  __shared__ int pos[BKT];
  __shared__ int wtot[2];
  __shared__ int esrc_l[ESRC_CAP];
  __shared__ unsigned short aggl[8][16 * 64];
  const int b = blockIdx.x;
  const int tid = threadIdx.x, lane = tid & 63;
  const int wv = tid >> 6;

  if (tid < BKT) cnt[tid] = 0;
  __syncthreads();
  const int s0 = bktStart[b], ne = bktTot[b];
  for (int i = tid; i < ne; i += 512)
    atomicAdd(&cnt[binned[s0 + i] >> DL_SHIFT], 1);
  __syncthreads();
  // scan 128 counters (2 waves of shuffles)
  int c = 0, inc = 0;
  if (tid < BKT) {
    c = cnt[tid]; inc = c;
    #pragma unroll
    for (int d = 1; d < 64; d <<= 1) { int y = __shfl_up(inc, d); if (lane >= d) inc += y; }
    if (lane == 63) wtot[tid >> 6] = inc;
  }
  __syncthreads();
  if (tid < BKT) {
    int ex = inc - c + ((tid >= 64) ? wtot[0] : 0);
    st[tid] = ex; pos[tid] = ex;
  }
  __syncthreads();
  // place into LDS edge list
  for (int i = tid; i < ne; i += 512) {
    int pe = binned[s0 + i];
    int p = atomicAdd(&pos[pe >> DL_SHIFT], 1);
    if (p < ESRC_CAP) esrc_l[p] = pe & SRC_MASK;
  }
  __syncthreads();

  // ---- agg: wave wv owns local rows [wv*16, wv*16+16); 8 lanes per node ----
  unsigned short* lw = &aggl[wv][0];
  const int n = lane >> 3;
  const int h = lane & 7;

  #pragma unroll
  for (int half = 0; half < 2; ++half) {
    const int row = half * 8 + n;              // 0..15
    const int lnode = wv * 16 + row;           // 0..127
    const int o0 = st[lnode];
    const int dg = cnt[lnode];
    const int o1 = o0 + dg;
    float a[8];
    #pragma unroll
    for (int q = 0; q < 8; q++) a[q] = 0.f;

    int i = o0;
    for (; i + 4 <= o1; i += 4) {
      int s0e = esrc_l[i], s1e = esrc_l[i + 1], s2e = esrc_l[i + 2], s3e = esrc_l[i + 3];
      uint4 v0 = *(const uint4*)(featb + s0e * 64 + h * 8);
      uint4 v1 = *(const uint4*)(featb + s1e * 64 + h * 8);
      uint4 v2 = *(const uint4*)(featb + s2e * 64 + h * 8);
      uint4 v3 = *(const uint4*)(featb + s3e * 64 + h * 8);
      acc_add(a, v0); acc_add(a, v1); acc_add(a, v2); acc_add(a, v3);
    }
    if (i < o1) {                               // masked quad: 1..3 remaining
      int last = o1 - 1;
      int e1 = min(i + 1, last), e2 = min(i + 2, last);
      float m1 = (i + 1 < o1) ? 1.f : 0.f;
      float m2 = (i + 2 < o1) ? 1.f : 0.f;
      int s0e = esrc_l[i], s1e = esrc_l[e1], s2e = esrc_l[e2];
      uint4 v0 = *(const uint4*)(featb + s0e * 64 + h * 8);
      uint4 v1 = *(const uint4*)(featb + s1e * 64 + h * 8);
      uint4 v2 = *(const uint4*)(featb + s2e * 64 + h * 8);
      acc_add(a, v0); acc_fma(a, v1, m1); acc_fma(a, v2, m2);
    }

    const float inv = (dg > 0) ? (1.0f / (float)dg) : 0.f;
    unsigned d0 = ((unsigned)f2bf(a[1] * inv) << 16) | f2bf(a[0] * inv);
    unsigned d1 = ((unsigned)f2bf(a[3] * inv) << 16) | f2bf(a[2] * inv);
    unsigned d2 = ((unsigned)f2bf(a[5] * inv) << 16) | f2bf(a[4] * inv);
    unsigned d3 = ((unsigned)f2bf(a[7] * inv) << 16) | f2bf(a[6] * inv);
    *(uint4*)(lw + row * 64 + ((h ^ (row & 7)) << 3)) = make_uint4(d0, d1, d2, d3);
  }

  // same-wave LDS RAW: DS pipe is per-wave in-order; pin compiler ordering
  __builtin_amdgcn_wave_barrier();
  asm volatile("" ::: "memory");

  // ---- xform: 16x64 @ 64x64 via 16 MFMAs ----
  const int tbase = (b << BKT_SHIFT) + wv * 16;
  if (tbase >= N_NODES) return;                 // last bucket has 32 valid nodes
  const int col = lane & 15, rr = lane >> 4;
  const int m = tbase + col;
  short8 as0 = *(const short8*)(featb + m * 64 + rr * 8);
  short8 as1 = *(const short8*)(featb + m * 64 + 32 + rr * 8);
  short8 aa0 = *(const short8*)(lw + col * 64 + ((rr ^ (col & 7)) << 3));
  short8 aa1 = *(const short8*)(lw + col * 64 + (((rr + 4) ^ (col & 7)) << 3));

  #pragma unroll
  for (int nt = 0; nt < 4; nt++) {
    short8 bs0 = *(const short8*)(wfS + ((0 * 4 + nt) * 64 + lane) * 8);
    short8 bs1 = *(const short8*)(wfS + ((1 * 4 + nt) * 64 + lane) * 8);
    short8 bn0 = *(const short8*)(wfN + ((0 * 4 + nt) * 64 + lane) * 8);
    short8 bn1 = *(const short8*)(wfN + ((1 * 4 + nt) * 64 + lane) * 8);
    float bvn = bias[nt * 16 + col];
    float4v cfr = {bvn, bvn, bvn, bvn};
    cfr = __builtin_amdgcn_mfma_f32_16x16x32_bf16(as0, bs0, cfr, 0, 0, 0);
    cfr = __builtin_amdgcn_mfma_f32_16x16x32_bf16(as1, bs1, cfr, 0, 0, 0);
    cfr = __builtin_amdgcn_mfma_f32_16x16x32_bf16(aa0, bn0, cfr, 0, 0, 0);
    cfr = __builtin_amdgcn_mfma_f32_16x16x32_bf16(aa1, bn1, cfr, 0, 0, 0);
    #pragma unroll
    for (int r2 = 0; r2 < 4; r2++) {
      int row = tbase + rr * 4 + r2;
      float v = cfr[r2];
      if (RELU) v = fmaxf(v, 0.f);
      if (OUT_BF) outb[row * 64 + nt * 16 + col] = f2bf(v);
      else        outf[row * 64 + nt * 16 + col] = v;
    }
  }
}

// ---- launch ----------------------------------------------------------------

extern "C" void kernel_launch(void* const* d_in, const int* in_sizes, int n_in,
                              void* d_out, int out_size, void* d_ws, size_t ws_size,
                              hipStream_t stream) {
  const float* x   = (const float*)d_in[0];
  const int*   src = (const int*)d_in[1];
  const int*   dst = (const int*)d_in[2];
  const float* Ws1 = (const float*)d_in[3];
  const float* Wn1 = (const float*)d_in[4];
  const float* b1  = (const float*)d_in[5];
  const float* Ws2 = (const float*)d_in[6];
  const float* Wn2 = (const float*)d_in[7];
  const float* b2  = (const float*)d_in[8];

  char* ws = (char*)d_ws;
  int*            blkCnt   = (int*)(ws + 0);              // NBKT*256 ints (800,768 B)
  int*            bktTot   = (int*)(ws + 800768);         // NBKT ints
  int*            bktStart = (int*)(ws + 803896);         // NBKT ints
  unsigned short* wf       = (unsigned short*)(ws + 807024);    // 32 KB
  int*            binned   = (int*)(ws + 839792);         // E ints (6.4 MB)
  unsigned short* xbf      = (unsigned short*)(ws + 7239792);   // N*64 bf16 (12.8 MB)
  unsigned short* hbf      = (unsigned short*)(ws + 20039792);  // N*64 bf16 (12.8 MB)

  k_prep_count<<<CNT_BLOCKS + 4 + CVT_BLOCKS, 256, 0, stream>>>(
      x, xbf, Ws1, Wn1, Ws2, Wn2, wf, dst, blkCnt);
  kA_scan1<<<NBKT, CNT_BLOCKS, 0, stream>>>(blkCnt, bktTot);
  k_scatter<<<CNT_BLOCKS, 512, 0, stream>>>(src, dst, blkCnt, bktTot, bktStart, binned);

  k_fusedB<true, true><<<NBKT, 512, 0, stream>>>(xbf, binned, bktStart, bktTot,
                                                 wf + 0 * 4096, wf + 1 * 4096, b1,
                                                 nullptr, hbf);
  k_fusedB<false, false><<<NBKT, 512, 0, stream>>>(hbf, binned, bktStart, bktTot,
                                                   wf + 2 * 4096, wf + 3 * 4096, b2,
                                                   (float*)d_out, nullptr);
}

// Round 9
// 195.683 us; speedup vs baseline: 1.1873x; 1.1873x over previous
//
#include <hip/hip_runtime.h>

#define N_NODES 100000
#define N_EDGES 1600000
#define NBKT 196          // ceil(100000 / 512)
#define BKT_SHIFT 9
#define BKT_MASK 511
#define DL_SHIFT 17
#define SRC_MASK 0x1FFFF
#define NT_TILES 6250     // N_NODES / 16
#define CNT_BLOCKS 256
#define CVT_BLOCKS 1563   // 1563*256*4 float4 >= 1.6M float4

typedef __attribute__((ext_vector_type(8))) short short8;
typedef __attribute__((ext_vector_type(4))) float float4v;

__device__ __forceinline__ unsigned short f2bf(float f) {  // RNE
  unsigned u = __float_as_uint(f);
  return (unsigned short)((u + 0x7fffu + ((u >> 16) & 1u)) >> 16);
}
__device__ __forceinline__ float bflo(unsigned d) { return __uint_as_float(d << 16); }
__device__ __forceinline__ float bfhi(unsigned d) { return __uint_as_float(d & 0xffff0000u); }

__device__ __forceinline__ void acc_add(float a[8], uint4 v) {
  a[0] += bflo(v.x); a[1] += bfhi(v.x);
  a[2] += bflo(v.y); a[3] += bfhi(v.y);
  a[4] += bflo(v.z); a[5] += bfhi(v.z);
  a[6] += bflo(v.w); a[7] += bfhi(v.w);
}
__device__ __forceinline__ void acc_fma(float a[8], uint4 v, float m) {
  a[0] = fmaf(m, bflo(v.x), a[0]); a[1] = fmaf(m, bfhi(v.x), a[1]);
  a[2] = fmaf(m, bflo(v.y), a[2]); a[3] = fmaf(m, bfhi(v.y), a[3]);
  a[4] = fmaf(m, bflo(v.z), a[4]); a[5] = fmaf(m, bfhi(v.z), a[5]);
  a[6] = fmaf(m, bflo(v.w), a[6]); a[7] = fmaf(m, bfhi(v.w), a[7]);
}

// ---- K1: bucket count (LDS hist, first) + weight pre-swizzle + cvt ---------

__global__ void k_prep_count(const float* __restrict__ in, unsigned short* __restrict__ outb,
                             const float* __restrict__ W0, const float* __restrict__ W1,
                             const float* __restrict__ W2, const float* __restrict__ W3,
                             unsigned short* __restrict__ F,
                             const int* __restrict__ dst, int* __restrict__ blkCnt) {
  __shared__ int hist[NBKT];
  const int bid = blockIdx.x;
  if (bid < CNT_BLOCKS) {
    for (int t = threadIdx.x; t < NBKT; t += 256) hist[t] = 0;
    __syncthreads();
    const int e0 = bid * (N_EDGES / CNT_BLOCKS);
    const int e1 = e0 + (N_EDGES / CNT_BLOCKS);
    for (int e = e0 + threadIdx.x; e < e1; e += 256)
      atomicAdd(&hist[dst[e] >> BKT_SHIFT], 1);
    __syncthreads();
    for (int t = threadIdx.x; t < NBKT; t += 256)
      blkCnt[t * CNT_BLOCKS + bid] = hist[t];
    return;
  }
  if (bid < CNT_BLOCKS + 4) {
    // weight pre-swizzle into MFMA B-fragment order
    if (threadIdx.x >= 64) return;
    const int wsel = bid - CNT_BLOCKS;
    const float* W = (wsel == 0) ? W0 : (wsel == 1) ? W1 : (wsel == 2) ? W2 : W3;
    unsigned short* out = F + wsel * 4096;
    int lane = threadIdx.x;
    int col = lane & 15, kr = lane >> 4;
    #pragma unroll
    for (int kc = 0; kc < 2; kc++)
      #pragma unroll
      for (int nt = 0; nt < 4; nt++) {
        unsigned d[4];
        #pragma unroll
        for (int jj = 0; jj < 4; jj++) {
          float w0 = W[(kc * 32 + kr * 8 + 2 * jj)     * 64 + nt * 16 + col];
          float w1 = W[(kc * 32 + kr * 8 + 2 * jj + 1) * 64 + nt * 16 + col];
          d[jj] = ((unsigned)f2bf(w1) << 16) | f2bf(w0);
        }
        uint4* p = (uint4*)(out + ((kc * 4 + nt) * 64 + lane) * 8);
        *p = make_uint4(d[0], d[1], d[2], d[3]);
      }
    return;
  }
  // cvt: 4 float4 per thread (coalesced per sub-iter); 1.6M float4 total
  const int base = (bid - CNT_BLOCKS - 4) * 1024 + threadIdx.x;
  #pragma unroll
  for (int j = 0; j < 4; j++) {
    int i = base + j * 256;
    if (i < 1600000) {
      float4 v = ((const float4*)in)[i];
      unsigned d0 = ((unsigned)f2bf(v.y) << 16) | f2bf(v.x);
      unsigned d1 = ((unsigned)f2bf(v.w) << 16) | f2bf(v.z);
      ((uint2*)outb)[i] = make_uint2(d0, d1);
    }
  }
}

// ---- K2: per-bucket exclusive scan of per-block counts (R2-verbatim) -------

__global__ void kA_scan1(int* __restrict__ blkCnt, int* __restrict__ bktTot) {
  const int b = blockIdx.x;
  const int tid = threadIdx.x, lane = tid & 63, w = tid >> 6;
  int v = blkCnt[b * CNT_BLOCKS + tid];
  int inc = v;
  #pragma unroll
  for (int d = 1; d < 64; d <<= 1) { int y = __shfl_up(inc, d); if (lane >= d) inc += y; }
  __shared__ int wtot[4];
  if (lane == 63) wtot[w] = inc;
  __syncthreads();
  int base = 0;
  for (int j = 0; j < w; j++) base += wtot[j];
  blkCnt[b * CNT_BLOCKS + tid] = base + inc - v;
  if (tid == CNT_BLOCKS - 1) bktTot[b] = base + inc;
}

// ---- K3: scatter into bucket-grouped binned (R2-verbatim) ------------------

__global__ void kA_scatter(const int* __restrict__ src, const int* __restrict__ dst,
                           const int* __restrict__ blkCnt, const int* __restrict__ bktTot,
                           int* __restrict__ bktStart, int* __restrict__ binned) {
  __shared__ int ps[NBKT];
  __shared__ int curb[NBKT];
  const int tid = threadIdx.x;
  if (tid < 64) {
    int running = 0;
    for (int base = 0; base < NBKT; base += 64) {
      int i = base + tid;
      int v = (i < NBKT) ? bktTot[i] : 0;
      int inc = v;
      #pragma unroll
      for (int d = 1; d < 64; d <<= 1) { int y = __shfl_up(inc, d); if (tid >= d) inc += y; }
      if (i < NBKT) ps[i] = running + inc - v;
      running += __shfl(inc, 63);
    }
  }
  __syncthreads();
  for (int t = tid; t < NBKT; t += 256)
    curb[t] = ps[t] + blkCnt[t * CNT_BLOCKS + blockIdx.x];
  if (blockIdx.x == 0)
    for (int t = tid; t < NBKT; t += 256) bktStart[t] = ps[t];
  __syncthreads();
  const int e0 = blockIdx.x * (N_EDGES / CNT_BLOCKS);
  const int e1 = e0 + (N_EDGES / CNT_BLOCKS);
  for (int e = e0 + tid; e < e1; e += 256) {
    int d = dst[e];
    int s = src[e];
    int b = d >> BKT_SHIFT;
    int p = atomicAdd(&curb[b], 1);
    binned[p] = s | ((d & BKT_MASK) << DL_SHIFT);   // src:17 | dlocal:9
  }
}

// ---- K4: merged counting sort per 512-node bucket, 512 threads -------------

__global__ __launch_bounds__(512)
void k_sort(const int* __restrict__ binned, const int* __restrict__ bktStart,
            const int* __restrict__ bktTot,
            int* __restrict__ off, int* __restrict__ esrc) {
  const int b = blockIdx.x;
  const int tid = threadIdx.x, lane = tid & 63, w = tid >> 6;
  __shared__ int cnt[512];
  __shared__ int pos[512];
  __shared__ int wtot[8];
  cnt[tid] = 0;
  __syncthreads();
  const int s0 = bktStart[b], ne = bktTot[b];
  for (int i = tid; i < ne; i += 512)
    atomicAdd(&cnt[binned[s0 + i] >> DL_SHIFT], 1);
  __syncthreads();
  // scan 512 counters, 1/thread across 8 waves
  int c = cnt[tid];
  int inc = c;
  #pragma unroll
  for (int d = 1; d < 64; d <<= 1) { int y = __shfl_up(inc, d); if (lane >= d) inc += y; }
  if (lane == 63) wtot[w] = inc;
  __syncthreads();
  int base = s0;
  for (int j = 0; j < w; j++) base += wtot[j];
  int ex = base + inc - c;          // global edge offset of node (b<<9)+tid
  pos[tid] = ex;
  int n0 = (b << BKT_SHIFT) + tid;
  if (n0 < N_NODES) off[n0] = ex;
  if (b == NBKT - 1 && tid == 0) off[N_NODES] = N_EDGES;
  if (b == NBKT - 1 && tid < 4) esrc[N_EDGES + tid] = 0;   // prefetch pad
  __syncthreads();
  for (int i = tid; i < ne; i += 512) {
    int pe = binned[s0 + i];
    int p = atomicAdd(&pos[pe >> DL_SHIFT], 1);
    esrc[p] = pe & SRC_MASK;
  }
}

// ---- fused per-layer: mean-aggregate 16 nodes -> LDS -> MFMA transform -----
// R2-proven structure (8 lanes/node, 4-wave 256-thr blocks, global CSR,
// 4-edge unroll) + index-prefetch software pipeline (esrc padded by 4).

template <bool RELU, bool OUT_BF>
__global__ void k_fused(const unsigned short* __restrict__ featb,
                        const int* __restrict__ off, const int* __restrict__ esrc,
                        const unsigned short* __restrict__ wfS,
                        const unsigned short* __restrict__ wfN,
                        const float* __restrict__ bias,
                        float* __restrict__ outf, unsigned short* __restrict__ outb) {
  // per-wave 16x64 bf16 agg tile, XOR-swizzled in 16B blocks:
  // row j, block bk stored at slot bk^(j&7)
  __shared__ unsigned short aggl[4][16 * 64];
  const int tid = threadIdx.x;
  const int lane = tid & 63;
  const int wslot = tid >> 6;
  const int t = (blockIdx.x * blockDim.x + tid) >> 6;   // one 16-node tile per wave
  if (t >= NT_TILES) return;

  unsigned short* lw = &aggl[wslot][0];
  const int n = lane >> 3;   // node slot (8 nodes in parallel)
  const int h = lane & 7;    // feature block (8 bf16 = 16B), exclusive ownership

  #pragma unroll
  for (int half = 0; half < 2; ++half) {
    const int row = half * 8 + n;          // tile-local row 0..15
    const int node = t * 16 + row;
    const int o0 = off[node];
    const int o1 = off[node + 1];
    float a[8];
    #pragma unroll
    for (int q = 0; q < 8; q++) a[q] = 0.f;

    // index-prefetch pipeline: indices for quad at i are already in registers
    // when its gathers issue; next quad's indices load under the gathers.
    int i = o0;
    int s0e = esrc[i], s1e = esrc[i + 1], s2e = esrc[i + 2], s3e = esrc[i + 3];
    for (; i + 4 <= o1; ) {
      uint4 v0 = *(const uint4*)(featb + s0e * 64 + h * 8);
      uint4 v1 = *(const uint4*)(featb + s1e * 64 + h * 8);
      uint4 v2 = *(const uint4*)(featb + s2e * 64 + h * 8);
      uint4 v3 = *(const uint4*)(featb + s3e * 64 + h * 8);
      i += 4;
      s0e = esrc[i]; s1e = esrc[i + 1]; s2e = esrc[i + 2]; s3e = esrc[i + 3];
      acc_add(a, v0); acc_add(a, v1); acc_add(a, v2); acc_add(a, v3);
    }
    if (i < o1) {                          // 1..3 remaining; indices prefetched
      const int rem = o1 - i;
      int t1 = (rem > 1) ? s1e : s0e;
      int t2 = (rem > 2) ? s2e : s0e;
      float m1 = (rem > 1) ? 1.f : 0.f;
      float m2 = (rem > 2) ? 1.f : 0.f;
      uint4 v0 = *(const uint4*)(featb + s0e * 64 + h * 8);
      uint4 v1 = *(const uint4*)(featb + t1 * 64 + h * 8);
      uint4 v2 = *(const uint4*)(featb + t2 * 64 + h * 8);
      acc_add(a, v0); acc_fma(a, v1, m1); acc_fma(a, v2, m2);
    }

    const int dg = o1 - o0;
    const float inv = (dg > 0) ? (1.0f / (float)dg) : 0.f;
    unsigned d0 = ((unsigned)f2bf(a[1] * inv) << 16) | f2bf(a[0] * inv);
    unsigned d1 = ((unsigned)f2bf(a[3] * inv) << 16) | f2bf(a[2] * inv);
    unsigned d2 = ((unsigned)f2bf(a[5] * inv) << 16) | f2bf(a[4] * inv);
    unsigned d3 = ((unsigned)f2bf(a[7] * inv) << 16) | f2bf(a[6] * inv);
    *(uint4*)(lw + row * 64 + ((h ^ (row & 7)) << 3)) = make_uint4(d0, d1, d2, d3);
  }

  // same-wave LDS RAW: DS pipe is per-wave in-order; pin compiler ordering
  __builtin_amdgcn_wave_barrier();
  asm volatile("" ::: "memory");

  // ---- xform phase: 16x64 @ 64x64 via 16 MFMAs ----
  const int col = lane & 15, rr = lane >> 4;
  const int m = t * 16 + col;
  short8 as0 = *(const short8*)(featb + m * 64 + rr * 8);
  short8 as1 = *(const short8*)(featb + m * 64 + 32 + rr * 8);
  short8 aa0 = *(const short8*)(lw + col * 64 + ((rr ^ (col & 7)) << 3));
  short8 aa1 = *(const short8*)(lw + col * 64 + (((rr + 4) ^ (col & 7)) << 3));

  #pragma unroll
  for (int nt = 0; nt < 4; nt++) {
    short8 bs0 = *(const short8*)(wfS + ((0 * 4 + nt) * 64 + lane) * 8);
    short8 bs1 = *(const short8*)(wfS + ((1 * 4 + nt) * 64 + lane) * 8);
    short8 bn0 = *(const short8*)(wfN + ((0 * 4 + nt) * 64 + lane) * 8);
    short8 bn1 = *(const short8*)(wfN + ((1 * 4 + nt) * 64 + lane) * 8);
    float bvn = bias[nt * 16 + col];
    float4v cfr = {bvn, bvn, bvn, bvn};
    cfr = __builtin_amdgcn_mfma_f32_16x16x32_bf16(as0, bs0, cfr, 0, 0, 0);
    cfr = __builtin_amdgcn_mfma_f32_16x16x32_bf16(as1, bs1, cfr, 0, 0, 0);
    cfr = __builtin_amdgcn_mfma_f32_16x16x32_bf16(aa0, bn0, cfr, 0, 0, 0);
    cfr = __builtin_amdgcn_mfma_f32_16x16x32_bf16(aa1, bn1, cfr, 0, 0, 0);
    #pragma unroll
    for (int r2 = 0; r2 < 4; r2++) {
      int row = t * 16 + rr * 4 + r2;
      float v = cfr[r2];
      if (RELU) v = fmaxf(v, 0.f);
      if (OUT_BF) outb[row * 64 + nt * 16 + col] = f2bf(v);
      else        outf[row * 64 + nt * 16 + col] = v;
    }
  }
}

// ---- launch ----------------------------------------------------------------

extern "C" void kernel_launch(void* const* d_in, const int* in_sizes, int n_in,
                              void* d_out, int out_size, void* d_ws, size_t ws_size,
                              hipStream_t stream) {
  const float* x   = (const float*)d_in[0];
  const int*   src = (const int*)d_in[1];
  const int*   dst = (const int*)d_in[2];
  const float* Ws1 = (const float*)d_in[3];
  const float* Wn1 = (const float*)d_in[4];
  const float* b1  = (const float*)d_in[5];
  const float* Ws2 = (const float*)d_in[6];
  const float* Wn2 = (const float*)d_in[7];
  const float* b2  = (const float*)d_in[8];

  char* ws = (char*)d_ws;
  int*            blkCnt   = (int*)(ws + 0);              // 196*256 ints (200,704 B)
  int*            bktTot   = (int*)(ws + 200704);         // 196 ints
  int*            bktStart = (int*)(ws + 201488);         // 196 ints
  unsigned short* wf       = (unsigned short*)(ws + 202272);    // 32 KB
  int*            off      = (int*)(ws + 235040);         // N+1 ints
  int*            binned   = (int*)(ws + 635072);         // E ints (6.4 MB)
  int*            esrc     = (int*)(ws + 7035072);        // E+4 ints (6.4 MB)
  unsigned short* xbf      = (unsigned short*)(ws + 13435136);  // N*64 bf16
  unsigned short* hbf      = (unsigned short*)(ws + 26235136);  // N*64 bf16

  k_prep_count<<<CNT_BLOCKS + 4 + CVT_BLOCKS, 256, 0, stream>>>(
      x, xbf, Ws1, Wn1, Ws2, Wn2, wf, dst, blkCnt);
  kA_scan1<<<NBKT, CNT_BLOCKS, 0, stream>>>(blkCnt, bktTot);
  kA_scatter<<<CNT_BLOCKS, 256, 0, stream>>>(src, dst, blkCnt, bktTot, bktStart, binned);
  k_sort<<<NBKT, 512, 0, stream>>>(binned, bktStart, bktTot, off, esrc);

  k_fused<true, true><<<1563, 256, 0, stream>>>(xbf, off, esrc, wf + 0 * 4096,
                                                wf + 1 * 4096, b1, nullptr, hbf);
  k_fused<false, false><<<1563, 256, 0, stream>>>(hbf, off, esrc, wf + 2 * 4096,
                                                  wf + 3 * 4096, b2, (float*)d_out, nullptr);
}